// Round 19
// baseline (5419.884 us; speedup 1.0000x reference)
//
#include <hip/hip_runtime.h>
#include <math.h>

#define T_STEPS 512
#define BATCH   64
#define IDIM    512
#define DDIM    1024
#define KH      1024
#define KX      512
#define KT      1536
#define NBLK    256

typedef unsigned short ushort_t;
typedef unsigned long long ull_t;
typedef __attribute__((ext_vector_type(8))) short short8;
typedef __attribute__((ext_vector_type(4))) short short4v;
typedef __attribute__((ext_vector_type(4))) float f32x4;

#define POISON 0x7F7F7F7F7F7F7F7FULL

union U16B { ull_t u[2]; short8 s; };

__device__ __forceinline__ ushort_t f2bf(float f) {
    unsigned int u = __float_as_uint(f);
    u += 0x7fff + ((u >> 16) & 1);          // RNE
    return (ushort_t)(u >> 16);
}
__device__ __forceinline__ float bf2f(ushort_t s) {
    return __uint_as_float(((unsigned int)s) << 16);
}

// ---------------------------------------------------------------------------
// One-time: weights -> Ab[dc 0..63][g 0..2][s 0..1][m 0..15][k 0..1535] bf16
// ---------------------------------------------------------------------------
__global__ __launch_bounds__(256) void k_build_A(const float* __restrict__ U,
                                                 const float* __restrict__ Ux,
                                                 const float* __restrict__ W,
                                                 const float* __restrict__ Wx,
                                                 ushort_t* __restrict__ Ab) {
    int blk = blockIdx.x;            // 0..191 = dc*3+g
    int dc = blk / 3, g = blk % 3;
    int tid = threadIdx.x;
    int m = tid & 15, kb = tid >> 4;
    int col = dc * 16 + m;
    size_t rowbase = ((((size_t)dc * 3 + g) * 2 + 0) * 16 + m) * KT;
    for (int k = kb; k < KT; k += 16) {
        float w;
        if (g == 2) {
            w = (k < KH) ? Ux[(size_t)k * DDIM + col]
                         : Wx[(size_t)(k - KH) * DDIM + col];
        } else {
            int c2 = col + (g == 1 ? DDIM : 0);
            w = (k < KH) ? U[(size_t)k * (2 * DDIM) + c2]
                         : W[(size_t)(k - KH) * (2 * DDIM) + c2];
        }
        ushort_t w1 = f2bf(w);
        ushort_t w2 = f2bf(w - bf2f(w1));
        Ab[rowbase + k] = w1;
        Ab[rowbase + (size_t)16 * KT + k] = w2;   // s=1 (unused)
    }
}

// ---------------------------------------------------------------------------
// One-time: state_below -> sbB[t][s][b 0..63][i 0..511] bf16 (split pair)
// ---------------------------------------------------------------------------
__global__ __launch_bounds__(256) void k_build_sbB(const float* __restrict__ sb,
                                                   ushort_t* __restrict__ sbB) {
    int blk = blockIdx.x;            // 0..2047 = t*4+bt
    int t = blk >> 2, bt = blk & 3;
    int tid = threadIdx.x;
    int r = tid >> 4, c = tid & 15;
    const float* src = sb + ((size_t)t * BATCH + bt * 16 + r) * IDIM;
    ushort_t* d1 = sbB + ((((size_t)t * 2 + 0) * 4 + bt) * 16 + r) * KX;
    ushort_t* d2 = sbB + ((((size_t)t * 2 + 1) * 4 + bt) * 16 + r) * KX;
#pragma unroll
    for (int rep = 0; rep < 8; ++rep) {
        int i = c * 4 + rep * 64;
        float4 v = *(const float4*)(src + i);
        ushort_t a0 = f2bf(v.x), a1 = f2bf(v.y), a2 = f2bf(v.z), a3 = f2bf(v.w);
        short4v p1 = {(short)a0, (short)a1, (short)a2, (short)a3};
        *(short4v*)(d1 + i) = p1;
        ushort_t b0 = f2bf(v.x - bf2f(a0)), b1 = f2bf(v.y - bf2f(a1));
        ushort_t b2 = f2bf(v.z - bf2f(a2)), b3 = f2bf(v.w - bf2f(a3));
        short4v p2 = {(short)b0, (short)b1, (short)b2, (short)b3};
        *(short4v*)(d2 + i) = p2;
    }
}

// ---------------------------------------------------------------------------
// POISON-path persistent scan: NO flags, NO barrier. h exchanged via
// write-once per-step buffers hAll[t] (pre-poisoned 0x7F). Consumers poll
// their own h words (8-B granularity = producer store granularity); a word
// != POISON is final. Data-as-flag: zero ordering assumptions.
// Grid 256 = (dc 0..63) x (bq 0..3) XCD-swizzled (r16 mapping); 768 thr =
// 12 waves; ku<8: h k-slice, ku>=8: x k-slice (never waits).
// ---------------------------------------------------------------------------
__global__ __launch_bounds__(768, 1) void k_scan_p(
    const ushort_t* __restrict__ Ab, const ushort_t* __restrict__ sbB,
    const float* __restrict__ mask, const float* __restrict__ bW,
    const float* __restrict__ bWx, ushort_t* __restrict__ hAll,
    float* __restrict__ out)
{
    __shared__ float red[12 * 3 * 4 * 64];   // 36,864 B

    int tid  = threadIdx.x;
    int lane = tid & 63;
    int ku   = tid >> 6;                 // 0..11 = K-slice
    int bid  = blockIdx.x;
    int xcd  = bid & 7, j = bid >> 3;    // j 0..31
    int dc   = xcd * 8 + (j & 7);        // 0..63
    int bq   = j >> 3;                   // 0..3

    int m = lane & 15, q = lane >> 4;
    int b_lane = bq * 16 + m;

    bool isH  = (ku < 8);
    int kbase = isH ? ku * 128 : KH + (ku - 8) * 128;

    // ---- A1 fragments: registers for the whole scan (3 g x 4 k-steps)
    short8 A1r[3][4];
#pragma unroll
    for (int g = 0; g < 3; ++g) {
        const ushort_t* a1p =
            Ab + ((((size_t)dc * 3 + g) * 2 + 0) * 16 + m) * KT + kbase;
#pragma unroll
        for (int ks = 0; ks < 4; ++ks)
            A1r[g][ks] = *(const short8*)(a1p + ks * 32 + q * 8);
    }

    // ---- epilogue persistent state: tid<256 owns (d = dc*16+dl, b = bq*16+b16)
    int dl = tid >> 4, b16 = tid & 15;   // valid for tid<256
    int ed = dc * 16 + (dl & 15), eb = bq * 16 + b16;
    int l_src = ((dl & 15) >> 2) * 16 + b16;
    int rg = dl & 3;
    float bR = 0.f, bU = 0.f, bX = 0.f, hold = 0.f;
    if (tid < 256) { bR = bW[ed]; bU = bW[DDIM + ed]; bX = bWx[ed]; }

    const size_t hP = (size_t)2 * 64 * KH;   // elems per step buffer

    for (int t = 0; t < T_STEPS; ++t) {
        ushort_t* hOut = hAll + (size_t)t * hP;

        f32x4 accA[3] = {{0,0,0,0},{0,0,0,0},{0,0,0,0}};
        f32x4 accB[3] = {{0,0,0,0},{0,0,0,0},{0,0,0,0}};

        if (isH) {
            if (t > 0) {
                const ushort_t* hIn = hAll + (size_t)(t - 1) * hP;
                const ushort_t* brow = hIn + (size_t)b_lane * KH + kbase;
                U16B x1[4], x2[4];
                // poll own data until all 16 words are non-poison (final)
                for (;;) {
                    bool ok = true;
#pragma unroll
                    for (int ks = 0; ks < 4; ++ks) {
                        int off = ks * 32 + q * 8;
                        const ull_t* p1 = (const ull_t*)(brow + off);
                        const ull_t* p2 = (const ull_t*)(brow + (size_t)64 * KH + off);
                        x1[ks].u[0] = __hip_atomic_load(p1, __ATOMIC_RELAXED,
                                                        __HIP_MEMORY_SCOPE_AGENT);
                        x1[ks].u[1] = __hip_atomic_load(p1 + 1, __ATOMIC_RELAXED,
                                                        __HIP_MEMORY_SCOPE_AGENT);
                        x2[ks].u[0] = __hip_atomic_load(p2, __ATOMIC_RELAXED,
                                                        __HIP_MEMORY_SCOPE_AGENT);
                        x2[ks].u[1] = __hip_atomic_load(p2 + 1, __ATOMIC_RELAXED,
                                                        __HIP_MEMORY_SCOPE_AGENT);
                        ok = ok && (x1[ks].u[0] != POISON) && (x1[ks].u[1] != POISON)
                                && (x2[ks].u[0] != POISON) && (x2[ks].u[1] != POISON);
                    }
                    if (__all(ok)) break;
                }
#pragma unroll
                for (int ks = 0; ks < 4; ++ks) {
#pragma unroll
                    for (int g = 0; g < 3; ++g) {
                        f32x4* acc = (ks & 1) ? &accB[g] : &accA[g];
                        *acc = __builtin_amdgcn_mfma_f32_16x16x32_bf16(A1r[g][ks], x2[ks].s, *acc, 0, 0, 0);
                        *acc = __builtin_amdgcn_mfma_f32_16x16x32_bf16(A1r[g][ks], x1[ks].s, *acc, 0, 0, 0);
                    }
                }
            }
        } else {
            const ushort_t* brow =
                sbB + (size_t)t * (2 * 64 * KX) + (size_t)b_lane * KX + (kbase - KH);
#pragma unroll
            for (int ks = 0; ks < 4; ++ks) {
                int off = ks * 32 + q * 8;
                short8 B1 = *(const short8*)(brow + off);
                short8 B2 = *(const short8*)(brow + (size_t)64 * KX + off);
#pragma unroll
                for (int g = 0; g < 3; ++g) {
                    f32x4* acc = (ks & 1) ? &accB[g] : &accA[g];
                    *acc = __builtin_amdgcn_mfma_f32_16x16x32_bf16(A1r[g][ks], B2, *acc, 0, 0, 0);
                    *acc = __builtin_amdgcn_mfma_f32_16x16x32_bf16(A1r[g][ks], B1, *acc, 0, 0, 0);
                }
            }
        }

#pragma unroll
        for (int g = 0; g < 3; ++g) {
            f32x4 s = accA[g] + accB[g];
#pragma unroll
            for (int r2 = 0; r2 < 4; ++r2)
                red[((ku * 3 + g) * 4 + r2) * 64 + lane] = s[r2];
        }
        __syncthreads();

        // ---- epilogue: 256 threads, one (d, b) each; hold in register
        if (tid < 256) {
            float sR = 0.f, sU = 0.f, sHu = 0.f, sXx = 0.f;
#pragma unroll
            for (int k2 = 0; k2 < 12; ++k2) {
                sR += red[((k2 * 3 + 0) * 4 + rg) * 64 + l_src];
                sU += red[((k2 * 3 + 1) * 4 + rg) * 64 + l_src];
                float v2 = red[((k2 * 3 + 2) * 4 + rg) * 64 + l_src];
                if (k2 < 8) sHu += v2; else sXx += v2;
            }
            float mk = mask[(t << 6) + eb];
            float r  = 1.f / (1.f + __expf(-(sR + bR)));
            float u  = 1.f / (1.f + __expf(-(sU + bU)));
            float hc = tanhf(sHu * r + sXx + bX);
            float hnv = u * hold + (1.f - u) * hc;
            hnv = mk * hnv + (1.f - mk) * hold;
            hold = hnv;

            out[(size_t)t * (BATCH * DDIM) + (size_t)eb * DDIM + ed] = hnv;
            ushort_t h1 = f2bf(hnv);
            ushort_t h2 = f2bf(hnv - bf2f(h1));
            __hip_atomic_store(hOut + (size_t)eb * KH + ed, h1,
                               __ATOMIC_RELAXED, __HIP_MEMORY_SCOPE_AGENT);
            __hip_atomic_store(hOut + (size_t)64 * KH + (size_t)eb * KH + ed, h2,
                               __ATOMIC_RELAXED, __HIP_MEMORY_SCOPE_AGENT);
        }

        __syncthreads();   // protects red for reuse next step
    }
}

// ---------------------------------------------------------------------------
// FALLBACK (ws too small): r16's proven kernel verbatim (3.42 ms).
// ---------------------------------------------------------------------------
__global__ __launch_bounds__(768, 1) void k_scan_fb(
    const ushort_t* __restrict__ Ab, const ushort_t* __restrict__ sbB,
    const float* __restrict__ mask, const float* __restrict__ bW,
    const float* __restrict__ bWx, ushort_t* __restrict__ hB,
    float* __restrict__ out, int* __restrict__ bar)
{
    __shared__ float red[12 * 3 * 4 * 64];
    __shared__ int lflag;

    int tid  = threadIdx.x;
    int lane = tid & 63;
    int ku   = tid >> 6;
    int bid  = blockIdx.x;
    int xcd  = bid & 7, j = bid >> 3;
    int dc   = xcd * 8 + (j & 7);
    int bq   = j >> 3;

    int m = lane & 15, q = lane >> 4;
    int b_lane = bq * 16 + m;

    bool isH  = (ku < 8);
    int kbase = isH ? ku * 128 : KH + (ku - 8) * 128;
    int gidx  = 384 + xcd * 16;

    short8 A1r[3][4];
#pragma unroll
    for (int g = 0; g < 3; ++g) {
        const ushort_t* a1p =
            Ab + ((((size_t)dc * 3 + g) * 2 + 0) * 16 + m) * KT + kbase;
#pragma unroll
        for (int ks = 0; ks < 4; ++ks)
            A1r[g][ks] = *(const short8*)(a1p + ks * 32 + q * 8);
    }

    int dl = tid >> 4, b16 = tid & 15;
    int ed = dc * 16 + (dl & 15), eb = bq * 16 + b16;
    int l_src = ((dl & 15) >> 2) * 16 + b16;
    int rg = dl & 3;
    float bR = 0.f, bU = 0.f, bX = 0.f, hold = 0.f;
    if (tid < 256) { bR = bW[ed]; bU = bW[DDIM + ed]; bX = bWx[ed]; }

    if (tid == 0) lflag = 0;
    __syncthreads();

    const size_t hP = (size_t)2 * 64 * KH;

    for (int t = 0; t < T_STEPS; ++t) {
        const ushort_t* hBin  = hB + (size_t)(t & 1) * hP;
        ushort_t*       hBout = hB + (size_t)((t + 1) & 1) * hP;

        f32x4 accA[3] = {{0,0,0,0},{0,0,0,0},{0,0,0,0}};
        f32x4 accB[3] = {{0,0,0,0},{0,0,0,0},{0,0,0,0}};

        if (isH) {
            if (t > 0) {
                if (ku == 0) {
                    while (__hip_atomic_load(&bar[gidx], __ATOMIC_RELAXED,
                                             __HIP_MEMORY_SCOPE_AGENT) < t)
                        __builtin_amdgcn_s_sleep(1);
                    if (lane == 0)
                        __hip_atomic_store(&lflag, t, __ATOMIC_RELAXED,
                                           __HIP_MEMORY_SCOPE_WORKGROUP);
                } else {
                    while (__hip_atomic_load(&lflag, __ATOMIC_RELAXED,
                                             __HIP_MEMORY_SCOPE_WORKGROUP) < t)
                        __builtin_amdgcn_s_sleep(1);
                }
                const ushort_t* brow = hBin + (size_t)b_lane * KH + kbase;
#pragma unroll
                for (int ks = 0; ks < 4; ++ks) {
                    int off = ks * 32 + q * 8;
                    U16B x1, x2;
                    x1.u[0] = __hip_atomic_load((ull_t*)(brow + off),
                                                __ATOMIC_RELAXED, __HIP_MEMORY_SCOPE_AGENT);
                    x1.u[1] = __hip_atomic_load((ull_t*)(brow + off) + 1,
                                                __ATOMIC_RELAXED, __HIP_MEMORY_SCOPE_AGENT);
                    x2.u[0] = __hip_atomic_load((ull_t*)(brow + (size_t)64 * KH + off),
                                                __ATOMIC_RELAXED, __HIP_MEMORY_SCOPE_AGENT);
                    x2.u[1] = __hip_atomic_load((ull_t*)(brow + (size_t)64 * KH + off) + 1,
                                                __ATOMIC_RELAXED, __HIP_MEMORY_SCOPE_AGENT);
                    short8 B1 = x1.s, B2 = x2.s;
#pragma unroll
                    for (int g = 0; g < 3; ++g) {
                        f32x4* acc = (ks & 1) ? &accB[g] : &accA[g];
                        *acc = __builtin_amdgcn_mfma_f32_16x16x32_bf16(A1r[g][ks], B2, *acc, 0, 0, 0);
                        *acc = __builtin_amdgcn_mfma_f32_16x16x32_bf16(A1r[g][ks], B1, *acc, 0, 0, 0);
                    }
                }
            }
        } else {
            const ushort_t* brow =
                sbB + (size_t)t * (2 * 64 * KX) + (size_t)b_lane * KX + (kbase - KH);
#pragma unroll
            for (int ks = 0; ks < 4; ++ks) {
                int off = ks * 32 + q * 8;
                short8 B1 = *(const short8*)(brow + off);
                short8 B2 = *(const short8*)(brow + (size_t)64 * KX + off);
#pragma unroll
                for (int g = 0; g < 3; ++g) {
                    f32x4* acc = (ks & 1) ? &accB[g] : &accA[g];
                    *acc = __builtin_amdgcn_mfma_f32_16x16x32_bf16(A1r[g][ks], B2, *acc, 0, 0, 0);
                    *acc = __builtin_amdgcn_mfma_f32_16x16x32_bf16(A1r[g][ks], B1, *acc, 0, 0, 0);
                }
            }
        }

#pragma unroll
        for (int g = 0; g < 3; ++g) {
            f32x4 s = accA[g] + accB[g];
#pragma unroll
            for (int r2 = 0; r2 < 4; ++r2)
                red[((ku * 3 + g) * 4 + r2) * 64 + lane] = s[r2];
        }
        __syncthreads();

        if (tid < 256) {
            float sR = 0.f, sU = 0.f, sHu = 0.f, sXx = 0.f;
#pragma unroll
            for (int k2 = 0; k2 < 12; ++k2) {
                sR += red[((k2 * 3 + 0) * 4 + rg) * 64 + l_src];
                sU += red[((k2 * 3 + 1) * 4 + rg) * 64 + l_src];
                float v2 = red[((k2 * 3 + 2) * 4 + rg) * 64 + l_src];
                if (k2 < 8) sHu += v2; else sXx += v2;
            }
            float mk = mask[(t << 6) + eb];
            float r  = 1.f / (1.f + __expf(-(sR + bR)));
            float u  = 1.f / (1.f + __expf(-(sU + bU)));
            float hc = tanhf(sHu * r + sXx + bX);
            float hnv = u * hold + (1.f - u) * hc;
            hnv = mk * hnv + (1.f - mk) * hold;
            hold = hnv;

            out[(size_t)t * (BATCH * DDIM) + (size_t)eb * DDIM + ed] = hnv;
            ushort_t h1 = f2bf(hnv);
            ushort_t h2 = f2bf(hnv - bf2f(h1));
            __hip_atomic_store(hBout + (size_t)eb * KH + ed, h1,
                               __ATOMIC_RELAXED, __HIP_MEMORY_SCOPE_AGENT);
            __hip_atomic_store(hBout + (size_t)64 * KH + (size_t)eb * KH + ed, h2,
                               __ATOMIC_RELAXED, __HIP_MEMORY_SCOPE_AGENT);
        }

        __syncthreads();

        if (t + 1 < T_STEPS) {
            if (tid == 0)
                __hip_atomic_store(&bar[bid], t + 1, __ATOMIC_RELAXED,
                                   __HIP_MEMORY_SCOPE_AGENT);
            if (bid == 0 && ku == 0) {
                int need = t + 1;
                for (;;) {
                    int v0 = __hip_atomic_load(&bar[lane * 4 + 0], __ATOMIC_RELAXED,
                                               __HIP_MEMORY_SCOPE_AGENT);
                    int v1 = __hip_atomic_load(&bar[lane * 4 + 1], __ATOMIC_RELAXED,
                                               __HIP_MEMORY_SCOPE_AGENT);
                    int v2 = __hip_atomic_load(&bar[lane * 4 + 2], __ATOMIC_RELAXED,
                                               __HIP_MEMORY_SCOPE_AGENT);
                    int v3 = __hip_atomic_load(&bar[lane * 4 + 3], __ATOMIC_RELAXED,
                                               __HIP_MEMORY_SCOPE_AGENT);
                    int mn = min(min(v0, v1), min(v2, v3));
                    if (__all(mn >= need)) break;
                }
                if (lane < 8)
                    __hip_atomic_store(&bar[384 + lane * 16], need, __ATOMIC_RELAXED,
                                       __HIP_MEMORY_SCOPE_AGENT);
            }
        }
    }
}

// ---------------------------------------------------------------------------
extern "C" void kernel_launch(void* const* d_in, const int* in_sizes, int n_in,
                              void* d_out, int out_size, void* d_ws, size_t ws_size,
                              hipStream_t stream) {
    const float* sb   = (const float*)d_in[0];
    const float* mask = (const float*)d_in[1];
    const float* W    = (const float*)d_in[2];
    const float* bW   = (const float*)d_in[3];
    const float* Wx   = (const float*)d_in[4];
    const float* bWx  = (const float*)d_in[5];
    const float* U    = (const float*)d_in[6];
    const float* Ux   = (const float*)d_in[7];
    float* out = (float*)d_out;

    ushort_t* Ab  = (ushort_t*)d_ws;
    ushort_t* sbB = Ab + (size_t)2 * 3072 * KT;             // 18.87 MB
    ushort_t* tail = sbB + (size_t)T_STEPS * 2 * 64 * KX;   // +67.1 MB

    size_t base_bytes  = (size_t)(tail - (ushort_t*)d_ws) * 2;
    size_t hall_bytes  = (size_t)T_STEPS * 2 * 64 * KH * 2; // 134.2 MB

    k_build_A<<<dim3(192), 256, 0, stream>>>(U, Ux, W, Wx, Ab);
    k_build_sbB<<<dim3(T_STEPS * 4), 256, 0, stream>>>(sb, sbB);

    const ushort_t* AbC = Ab; const ushort_t* sbBC = sbB;

    if (ws_size >= base_bytes + hall_bytes) {
        // poison path: write-once per-step h buffers, no flags
        ushort_t* hAll = tail;
        (void)hipMemsetAsync(hAll, 0x7F, hall_bytes, stream);
        void* args[] = {(void*)&AbC, (void*)&sbBC, (void*)&mask, (void*)&bW,
                        (void*)&bWx, (void*)&hAll, (void*)&out};
        (void)hipLaunchCooperativeKernel((const void*)k_scan_p, dim3(NBLK),
                                         dim3(768), args, 0, stream);
    } else {
        // fallback: r16 proven checker+gen protocol (ping-pong h)
        ushort_t* hB  = tail;                               // 2 ping buffers
        int*      bar = (int*)(hB + (size_t)2 * 2 * 64 * KH);
        (void)hipMemsetAsync(bar, 0, 2048, stream);
        void* args[] = {(void*)&AbC, (void*)&sbBC, (void*)&mask, (void*)&bW,
                        (void*)&bWx, (void*)&hB, (void*)&out, (void*)&bar};
        (void)hipLaunchCooperativeKernel((const void*)k_scan_fb, dim3(NBLK),
                                         dim3(768), args, 0, stream);
    }
}

// Round 21
// 3392.372 us; speedup vs baseline: 1.5977x; 1.5977x over previous
//
#include <hip/hip_runtime.h>
#include <math.h>

#define T_STEPS 512
#define BATCH   64
#define IDIM    512
#define DDIM    1024
#define KH      1024
#define KX      512
#define KT      1536
#define NBLK    256

typedef unsigned short ushort_t;
typedef unsigned long long ull_t;
typedef __attribute__((ext_vector_type(8))) short short8;
typedef __attribute__((ext_vector_type(4))) short short4v;
typedef __attribute__((ext_vector_type(4))) float f32x4;

union U16B { ull_t u[2]; short8 s; };

__device__ __forceinline__ ushort_t f2bf(float f) {
    unsigned int u = __float_as_uint(f);
    u += 0x7fff + ((u >> 16) & 1);          // RNE
    return (ushort_t)(u >> 16);
}
__device__ __forceinline__ float bf2f(ushort_t s) {
    return __uint_as_float(((unsigned int)s) << 16);
}

// ---------------------------------------------------------------------------
// One-time: weights -> Ab[dc 0..63][g 0..2][s 0..1][m 0..15][k 0..1535] bf16
// ---------------------------------------------------------------------------
__global__ __launch_bounds__(256) void k_build_A(const float* __restrict__ U,
                                                 const float* __restrict__ Ux,
                                                 const float* __restrict__ W,
                                                 const float* __restrict__ Wx,
                                                 ushort_t* __restrict__ Ab) {
    int blk = blockIdx.x;            // 0..191 = dc*3+g
    int dc = blk / 3, g = blk % 3;
    int tid = threadIdx.x;
    int m = tid & 15, kb = tid >> 4;
    int col = dc * 16 + m;
    size_t rowbase = ((((size_t)dc * 3 + g) * 2 + 0) * 16 + m) * KT;
    for (int k = kb; k < KT; k += 16) {
        float w;
        if (g == 2) {
            w = (k < KH) ? Ux[(size_t)k * DDIM + col]
                         : Wx[(size_t)(k - KH) * DDIM + col];
        } else {
            int c2 = col + (g == 1 ? DDIM : 0);
            w = (k < KH) ? U[(size_t)k * (2 * DDIM) + c2]
                         : W[(size_t)(k - KH) * (2 * DDIM) + c2];
        }
        ushort_t w1 = f2bf(w);
        ushort_t w2 = f2bf(w - bf2f(w1));
        Ab[rowbase + k] = w1;
        Ab[rowbase + (size_t)16 * KT + k] = w2;   // s=1 (unused)
    }
}

// ---------------------------------------------------------------------------
// One-time: state_below -> sbB[t][s][b 0..63][i 0..511] bf16 (split pair)
// ---------------------------------------------------------------------------
__global__ __launch_bounds__(256) void k_build_sbB(const float* __restrict__ sb,
                                                   ushort_t* __restrict__ sbB) {
    int blk = blockIdx.x;            // 0..2047 = t*4+bt
    int t = blk >> 2, bt = blk & 3;
    int tid = threadIdx.x;
    int r = tid >> 4, c = tid & 15;
    const float* src = sb + ((size_t)t * BATCH + bt * 16 + r) * IDIM;
    ushort_t* d1 = sbB + ((((size_t)t * 2 + 0) * 4 + bt) * 16 + r) * KX;
    ushort_t* d2 = sbB + ((((size_t)t * 2 + 1) * 4 + bt) * 16 + r) * KX;
#pragma unroll
    for (int rep = 0; rep < 8; ++rep) {
        int i = c * 4 + rep * 64;
        float4 v = *(const float4*)(src + i);
        ushort_t a0 = f2bf(v.x), a1 = f2bf(v.y), a2 = f2bf(v.z), a3 = f2bf(v.w);
        short4v p1 = {(short)a0, (short)a1, (short)a2, (short)a3};
        *(short4v*)(d1 + i) = p1;
        ushort_t b0 = f2bf(v.x - bf2f(a0)), b1 = f2bf(v.y - bf2f(a1));
        ushort_t b2 = f2bf(v.z - bf2f(a2)), b3 = f2bf(v.w - bf2f(a3));
        short4v p2 = {(short)b0, (short)b1, (short)b2, (short)b3};
        *(short4v*)(d2 + i) = p2;
    }
}

// ---------------------------------------------------------------------------
// Persistent scan: r13 protocol + decontended gen broadcast (r16, proven).
// Grid 256 = (dc 0..63) x (bq 0..3) XCD-swizzled; 768 thr = 12 waves.
// Wave ku<8: h k-slice; ku>=8: x k-slice (never waits).
// End of step t: tid0 stores slots[bid]=t+1; checker (blk0 wave0) gathers
// all 256 slots, publishes gen to 8 XCD-local lines (bar[384+xcd*16]).
// Top of step t: block's wave ku=0 polls its XCD gen copy, releases ku=1..7
// via LDS flag; epilogue ordered after by the intra-block __syncthreads.
// bar ints: slots[0..255]; gen copies at 384+xcd*16.
// ---------------------------------------------------------------------------
__global__ __launch_bounds__(768, 1) void k_scan(
    const ushort_t* __restrict__ Ab, const ushort_t* __restrict__ sbB,
    const float* __restrict__ mask, const float* __restrict__ bW,
    const float* __restrict__ bWx, ushort_t* __restrict__ hB,
    float* __restrict__ out, int* __restrict__ bar)
{
    __shared__ float red[12 * 3 * 4 * 64];   // 36,864 B
    __shared__ int lflag;

    int tid  = threadIdx.x;
    int lane = tid & 63;
    int ku   = tid >> 6;                 // 0..11 = K-slice
    int bid  = blockIdx.x;
    int xcd  = bid & 7, j = bid >> 3;    // j 0..31
    int dc   = xcd * 8 + (j & 7);        // 0..63
    int bq   = j >> 3;                   // 0..3

    int m = lane & 15, q = lane >> 4;
    int b_lane = bq * 16 + m;

    bool isH  = (ku < 8);
    int kbase = isH ? ku * 128 : KH + (ku - 8) * 128;
    int gidx  = 384 + xcd * 16;          // this XCD's gen copy

    // ---- A1 fragments: registers for the whole scan (3 g x 4 k-steps)
    short8 A1r[3][4];
#pragma unroll
    for (int g = 0; g < 3; ++g) {
        const ushort_t* a1p =
            Ab + ((((size_t)dc * 3 + g) * 2 + 0) * 16 + m) * KT + kbase;
#pragma unroll
        for (int ks = 0; ks < 4; ++ks)
            A1r[g][ks] = *(const short8*)(a1p + ks * 32 + q * 8);
    }

    // ---- epilogue persistent state: tid<256 owns (d = dc*16+dl, b = bq*16+b16)
    int dl = tid >> 4, b16 = tid & 15;   // valid for tid<256
    int ed = dc * 16 + (dl & 15), eb = bq * 16 + b16;
    int l_src = ((dl & 15) >> 2) * 16 + b16;
    int rg = dl & 3;
    float bR = 0.f, bU = 0.f, bX = 0.f, hold = 0.f;
    if (tid < 256) { bR = bW[ed]; bU = bW[DDIM + ed]; bX = bWx[ed]; }

    if (tid == 0) lflag = 0;
    __syncthreads();

    const size_t hP = (size_t)2 * 64 * KH;   // elems per ping buffer

    for (int t = 0; t < T_STEPS; ++t) {
        const ushort_t* hBin  = hB + (size_t)(t & 1) * hP;
        ushort_t*       hBout = hB + (size_t)((t + 1) & 1) * hP;

        f32x4 accA[3] = {{0,0,0,0},{0,0,0,0},{0,0,0,0}};
        f32x4 accB[3] = {{0,0,0,0},{0,0,0,0},{0,0,0,0}};

        if (isH) {
            if (t > 0) {
                // wave ku=0 polls the XCD-local gen copy; others spin on LDS
                if (ku == 0) {
                    while (__hip_atomic_load(&bar[gidx], __ATOMIC_RELAXED,
                                             __HIP_MEMORY_SCOPE_AGENT) < t)
                        __builtin_amdgcn_s_sleep(1);
                    if (lane == 0)
                        __hip_atomic_store(&lflag, t, __ATOMIC_RELAXED,
                                           __HIP_MEMORY_SCOPE_WORKGROUP);
                } else {
                    while (__hip_atomic_load(&lflag, __ATOMIC_RELAXED,
                                             __HIP_MEMORY_SCOPE_WORKGROUP) < t)
                        __builtin_amdgcn_s_sleep(1);
                }
                const ushort_t* brow = hBin + (size_t)b_lane * KH + kbase;
#pragma unroll
                for (int ks = 0; ks < 4; ++ks) {
                    int off = ks * 32 + q * 8;
                    U16B x1, x2;
                    x1.u[0] = __hip_atomic_load((ull_t*)(brow + off),
                                                __ATOMIC_RELAXED, __HIP_MEMORY_SCOPE_AGENT);
                    x1.u[1] = __hip_atomic_load((ull_t*)(brow + off) + 1,
                                                __ATOMIC_RELAXED, __HIP_MEMORY_SCOPE_AGENT);
                    x2.u[0] = __hip_atomic_load((ull_t*)(brow + (size_t)64 * KH + off),
                                                __ATOMIC_RELAXED, __HIP_MEMORY_SCOPE_AGENT);
                    x2.u[1] = __hip_atomic_load((ull_t*)(brow + (size_t)64 * KH + off) + 1,
                                                __ATOMIC_RELAXED, __HIP_MEMORY_SCOPE_AGENT);
                    short8 B1 = x1.s, B2 = x2.s;
#pragma unroll
                    for (int g = 0; g < 3; ++g) {
                        f32x4* acc = (ks & 1) ? &accB[g] : &accA[g];
                        *acc = __builtin_amdgcn_mfma_f32_16x16x32_bf16(A1r[g][ks], B2, *acc, 0, 0, 0);
                        *acc = __builtin_amdgcn_mfma_f32_16x16x32_bf16(A1r[g][ks], B1, *acc, 0, 0, 0);
                    }
                }
            }
        } else {
            const ushort_t* brow =
                sbB + (size_t)t * (2 * 64 * KX) + (size_t)b_lane * KX + (kbase - KH);
#pragma unroll
            for (int ks = 0; ks < 4; ++ks) {
                int off = ks * 32 + q * 8;
                short8 B1 = *(const short8*)(brow + off);
                short8 B2 = *(const short8*)(brow + (size_t)64 * KX + off);
#pragma unroll
                for (int g = 0; g < 3; ++g) {
                    f32x4* acc = (ks & 1) ? &accB[g] : &accA[g];
                    *acc = __builtin_amdgcn_mfma_f32_16x16x32_bf16(A1r[g][ks], B2, *acc, 0, 0, 0);
                    *acc = __builtin_amdgcn_mfma_f32_16x16x32_bf16(A1r[g][ks], B1, *acc, 0, 0, 0);
                }
            }
        }

#pragma unroll
        for (int g = 0; g < 3; ++g) {
            f32x4 s = accA[g] + accB[g];
#pragma unroll
            for (int r2 = 0; r2 < 4; ++r2)
                red[((ku * 3 + g) * 4 + r2) * 64 + lane] = s[r2];
        }
        __syncthreads();

        // ---- epilogue: 256 threads, one (d, b) each; hold in register
        if (tid < 256) {
            float sR = 0.f, sU = 0.f, sHu = 0.f, sXx = 0.f;
#pragma unroll
            for (int k2 = 0; k2 < 12; ++k2) {
                sR += red[((k2 * 3 + 0) * 4 + rg) * 64 + l_src];
                sU += red[((k2 * 3 + 1) * 4 + rg) * 64 + l_src];
                float v2 = red[((k2 * 3 + 2) * 4 + rg) * 64 + l_src];
                if (k2 < 8) sHu += v2; else sXx += v2;
            }
            float mk = mask[(t << 6) + eb];
            float r  = 1.f / (1.f + __expf(-(sR + bR)));
            float u  = 1.f / (1.f + __expf(-(sU + bU)));
            float hc = tanhf(sHu * r + sXx + bX);
            float hnv = u * hold + (1.f - u) * hc;
            hnv = mk * hnv + (1.f - mk) * hold;
            hold = hnv;

            out[(size_t)t * (BATCH * DDIM) + (size_t)eb * DDIM + ed] = hnv;
            ushort_t h1 = f2bf(hnv);
            ushort_t h2 = f2bf(hnv - bf2f(h1));
            __hip_atomic_store(hBout + (size_t)eb * KH + ed, h1,
                               __ATOMIC_RELAXED, __HIP_MEMORY_SCOPE_AGENT);
            __hip_atomic_store(hBout + (size_t)64 * KH + (size_t)eb * KH + ed, h2,
                               __ATOMIC_RELAXED, __HIP_MEMORY_SCOPE_AGENT);
        }

        __syncthreads();   // drains every wave's stores (vmcnt0) before arrival

        if (t + 1 < T_STEPS) {
            if (tid == 0)
                __hip_atomic_store(&bar[bid], t + 1, __ATOMIC_RELAXED,
                                   __HIP_MEMORY_SCOPE_AGENT);
            if (bid == 0 && ku == 0) {
                // checker wave: gather all 256 slots, publish gen to 8 copies
                int need = t + 1;
                for (;;) {
                    int v0 = __hip_atomic_load(&bar[lane * 4 + 0], __ATOMIC_RELAXED,
                                               __HIP_MEMORY_SCOPE_AGENT);
                    int v1 = __hip_atomic_load(&bar[lane * 4 + 1], __ATOMIC_RELAXED,
                                               __HIP_MEMORY_SCOPE_AGENT);
                    int v2 = __hip_atomic_load(&bar[lane * 4 + 2], __ATOMIC_RELAXED,
                                               __HIP_MEMORY_SCOPE_AGENT);
                    int v3 = __hip_atomic_load(&bar[lane * 4 + 3], __ATOMIC_RELAXED,
                                               __HIP_MEMORY_SCOPE_AGENT);
                    int mn = min(min(v0, v1), min(v2, v3));
                    if (__all(mn >= need)) break;
                }
                if (lane < 8)
                    __hip_atomic_store(&bar[384 + lane * 16], need, __ATOMIC_RELAXED,
                                       __HIP_MEMORY_SCOPE_AGENT);
            }
        }
    }
}

// ---------------------------------------------------------------------------
extern "C" void kernel_launch(void* const* d_in, const int* in_sizes, int n_in,
                              void* d_out, int out_size, void* d_ws, size_t ws_size,
                              hipStream_t stream) {
    const float* sb   = (const float*)d_in[0];
    const float* mask = (const float*)d_in[1];
    const float* W    = (const float*)d_in[2];
    const float* bW   = (const float*)d_in[3];
    const float* Wx   = (const float*)d_in[4];
    const float* bWx  = (const float*)d_in[5];
    const float* U    = (const float*)d_in[6];
    const float* Ux   = (const float*)d_in[7];
    float* out = (float*)d_out;

    // ws layout (bf16 elems): Ab 9,437,184 | sbB 33,554,432 | hB 2x131,072 | bar
    ushort_t* Ab  = (ushort_t*)d_ws;
    ushort_t* sbB = Ab + (size_t)2 * 3072 * KT;
    ushort_t* hB  = sbB + (size_t)T_STEPS * 2 * 64 * KX;
    int*      bar = (int*)(hB + (size_t)2 * 2 * 64 * KH);

    (void)hipMemsetAsync(bar, 0, 2048, stream);   // covers slots + 8 gen copies
    k_build_A<<<dim3(192), 256, 0, stream>>>(U, Ux, W, Wx, Ab);
    k_build_sbB<<<dim3(T_STEPS * 4), 256, 0, stream>>>(sb, sbB);

    const ushort_t* AbC = Ab; const ushort_t* sbBC = sbB;
    void* args[] = {(void*)&AbC, (void*)&sbBC, (void*)&mask, (void*)&bW,
                    (void*)&bWx, (void*)&hB, (void*)&out, (void*)&bar};
    (void)hipLaunchCooperativeKernel((const void*)k_scan, dim3(NBLK), dim3(768),
                                     args, 0, stream);
}